// Round 9
// baseline (394.671 us; speedup 1.0000x reference)
//
#include <hip/hip_runtime.h>
#include <hip/hip_bf16.h>

#define BH   16
#define SEQ  2048
#define DH   64

typedef _Float16 f16;
typedef unsigned int u32;
using f32x4 = __attribute__((ext_vector_type(4))) float;
using f16x8 = __attribute__((ext_vector_type(8))) _Float16;
using f16x4 = __attribute__((ext_vector_type(4))) _Float16;

// ---------------- scratch map (first 4 KB "FH" of out_attn rows) ------------
// K   f16 [bh][k][d] : FH rows    0..1023  (chunk (bh*2048+k)>>5, off (k&31)*128+d*2)
// V^T f16 [bh][d][k] : FH rows 1024..2047  (row 1024+bh*64+d, off k*2)
// maskbits [bh][q][w]: FH rows 2048..4095  (256B per q-row: 64 u32 words)
// P' strips (f16) live in SECOND halves (bytes 4096..8191) of every row ->
// byte-disjoint. pass_b overwrites all rows last, so scratch never leaks.

// ============================ prep: K + V^T ============================
__global__ __launch_bounds__(256)
void mha_prep(const float* __restrict__ key, const float* __restrict__ value,
              char* __restrict__ scr)
{
  const int tid = threadIdx.x;
  if (blockIdx.x < 512) {           // ---- K path ----
    const int bh = blockIdx.x >> 5;
    const int k  = (blockIdx.x & 31) * 64 + (tid >> 2);
    const int ds = (tid & 3) * 16;
    const float* src = key + ((size_t)(bh * SEQ + k)) * DH + ds;
    f32x4 a0 = *(const f32x4*)(src);
    f32x4 a1 = *(const f32x4*)(src + 4);
    f32x4 a2 = *(const f32x4*)(src + 8);
    f32x4 a3 = *(const f32x4*)(src + 12);
    f16x8 h0, h1;
    #pragma unroll
    for (int e = 0; e < 4; ++e) {
      h0[e] = (f16)a0[e]; h0[4 + e] = (f16)a1[e];
      h1[e] = (f16)a2[e]; h1[4 + e] = (f16)a3[e];
    }
    char* dst = scr + ((size_t)((bh * SEQ + k) >> 5)) * 8192 + (k & 31) * 128 + ds * 2;
    *(f16x8*)dst        = h0;
    *(f16x8*)(dst + 16) = h1;
  } else {                          // ---- V^T path ----
    __shared__ f16 Vl[64][136];
    const int vb = blockIdx.x - 512;
    const int bh = vb >> 4;
    const int kc = (vb & 15) * 128;
    {
      const int kl = tid >> 1, dh = (tid & 1) * 32;
      const float* src = value + ((size_t)(bh * SEQ + kc + kl)) * DH + dh;
      f32x4 a[8];
      #pragma unroll
      for (int j = 0; j < 8; ++j) a[j] = *(const f32x4*)(src + j * 4);
      #pragma unroll
      for (int j = 0; j < 32; ++j) Vl[dh + j][kl] = (f16)a[j >> 2][j & 3];
    }
    __syncthreads();
    {
      const int d = tid >> 2, ks = (tid & 3) * 32;
      char* dst = scr + ((size_t)(1024 + bh * 64 + d)) * 8192 + (kc + ks) * 2;
      #pragma unroll
      for (int m = 0; m < 4; ++m)
        *(f16x8*)(dst + m * 16) = *(const f16x8*)&Vl[d][ks + m * 8];
    }
  }
}

// ============================ prep: mask bit-pack ============================
// thread T packs word T: 32 ints -> 1 u32. 268 MB read once at streaming BW.
__global__ __launch_bounds__(256)
void mha_packmask(const int* __restrict__ mask, char* __restrict__ scr)
{
  const int T = blockIdx.x * 256 + threadIdx.x;       // 0 .. 2M-1
  const int* src = mask + (size_t)T * 32;
  u32 bits = 0;
  #pragma unroll
  for (int c = 0; c < 8; ++c) {
    int4 m = *(const int4*)(src + c * 4);
    bits |= (m.x ? 1u : 0u) << (c * 4 + 0);
    bits |= (m.y ? 1u : 0u) << (c * 4 + 1);
    bits |= (m.z ? 1u : 0u) << (c * 4 + 2);
    bits |= (m.w ? 1u : 0u) << (c * 4 + 3);
  }
  const size_t L = (size_t)T * 4;
  *(u32*)(scr + ((size_t)2048 + (L >> 12)) * 8192 + (L & 4095)) = bits;
}

// ============================ pass A ============================
// Wave-autonomous; no LDS/barriers in the loop; ALL loop loads L2-resident
// (K, V^T, maskbits scratch: 2 MB per XCD). 8192 waves = 32/CU; VGPR<=64
// via launch_bounds(256,8) -> 8 waves/SIMD of TLP hide the L2 latency.
__global__ __launch_bounds__(256, 8)
void mha_pass_a(const char* __restrict__ kscr, const char* __restrict__ vscr,
                const char* __restrict__ pmscr,
                const float* __restrict__ query,
                const float* __restrict__ qmask,
                float* __restrict__ out_res, f16* __restrict__ strip)
{
  __shared__ float comb[3][64][17];
  const int tid  = threadIdx.x;
  const int lane = tid & 63;
  const int h    = tid >> 6;          // wave = k-quarter 0..3
  const int lr   = lane & 15;
  const int g    = lane >> 4;

  // XCD swizzle: 2048 blocks -> 256/XCD -> 2 bh per XCD (scratch L2-resident)
  const int idx = ((blockIdx.x & 7) << 8) + (blockIdx.x >> 3);
  const int bh  = idx >> 7;
  const int q0  = (idx & 127) << 4;

  // ---- Q fragments (f32 -> f16 registers) ----
  f16x8 qf0, qf1;
  {
    const float* qrow = query + ((size_t)(bh * SEQ + q0 + lr)) * DH;
    f32x4 a0 = *(const f32x4*)(qrow + g * 8);
    f32x4 a1 = *(const f32x4*)(qrow + g * 8 + 4);
    f32x4 a2 = *(const f32x4*)(qrow + 32 + g * 8);
    f32x4 a3 = *(const f32x4*)(qrow + 32 + g * 8 + 4);
    #pragma unroll
    for (int e = 0; e < 4; ++e) {
      qf0[e] = (f16)a0[e]; qf0[4 + e] = (f16)a1[e];
      qf1[e] = (f16)a2[e]; qf1[4 + e] = (f16)a3[e];
    }
  }

  f16* srow = strip + ((size_t)(bh * SEQ + q0 + lr)) * 4096 + 2048;
  const char* vrow = vscr + ((size_t)(1024 + bh * 64 + lr)) * 8192;
  const size_t L = ((size_t)((bh << 11) + q0 + lr)) << 8;
  const char* pmrow = pmscr + ((size_t)2048 + (L >> 12)) * 8192 + (L & 4095);

  f32x4 oacc[4];
  #pragma unroll
  for (int d = 0; d < 4; ++d) oacc[d] = (f32x4){0.f, 0.f, 0.f, 0.f};
  float lsum = 0.f;

  for (int K0 = h * 512; K0 < h * 512 + 512; K0 += 16) {
    // K fragment (L2): A[row=k-local=lr][d]; swapped QK -> D[kloc=g*4+i][q=lr]
    const char* ka = kscr + ((size_t)(((bh << 11) + K0) >> 5)) * 8192
                   + ((K0 & 31) + lr) * 128;
    f16x8 kf0 = *(const f16x8*)(ka + g * 16);
    f16x8 kf1 = *(const f16x8*)(ka + 64 + g * 16);
    // V^T fragments (L2) and mask word (L2) issued up front
    f16x4 vf0 = *(const f16x4*)(vrow +  0 * 8192 + (K0 + g * 4) * 2);
    f16x4 vf1 = *(const f16x4*)(vrow + 16 * 8192 + (K0 + g * 4) * 2);
    f16x4 vf2 = *(const f16x4*)(vrow + 32 * 8192 + (K0 + g * 4) * 2);
    f16x4 vf3 = *(const f16x4*)(vrow + 48 * 8192 + (K0 + g * 4) * 2);
    const u32 mw = *(const u32*)(pmrow + (K0 >> 5) * 4);

    f32x4 s = {0.f, 0.f, 0.f, 0.f};
    s = __builtin_amdgcn_mfma_f32_16x16x32_f16(kf0, qf0, s, 0, 0, 0);
    s = __builtin_amdgcn_mfma_f32_16x16x32_f16(kf1, qf1, s, 0, 0, 0);

    const int sh = (K0 & 16) + g * 4;
    const float p0 = ((mw >> (sh + 0)) & 1u) ? 0.f : __expf(s[0] * 0.125f);
    const float p1 = ((mw >> (sh + 1)) & 1u) ? 0.f : __expf(s[1] * 0.125f);
    const float p2 = ((mw >> (sh + 2)) & 1u) ? 0.f : __expf(s[2] * 0.125f);
    const float p3 = ((mw >> (sh + 3)) & 1u) ? 0.f : __expf(s[3] * 0.125f);
    lsum += (p0 + p1) + (p2 + p3);
    f16x4 pk = { (f16)p0, (f16)p1, (f16)p2, (f16)p3 };

    // unnormalized P' -> strip (8B lane-local store)
    *(f16x4*)&srow[K0 + g * 4] = pk;

    // PV: pk is the 16x16x16 B-frag; A-frag = V^T[d=dblk*16+lr][k=g*4..+4]
    oacc[0] = __builtin_amdgcn_mfma_f32_16x16x16f16(vf0, pk, oacc[0], 0, 0, 0);
    oacc[1] = __builtin_amdgcn_mfma_f32_16x16x16f16(vf1, pk, oacc[1], 0, 0, 0);
    oacc[2] = __builtin_amdgcn_mfma_f32_16x16x16f16(vf2, pk, oacc[2], 0, 0, 0);
    oacc[3] = __builtin_amdgcn_mfma_f32_16x16x16f16(vf3, pk, oacc[3], 0, 0, 0);
  }

  // ---- row partials -> combine 4 quarters (only barrier in the kernel) ----
  lsum += __shfl_xor(lsum, 16);
  lsum += __shfl_xor(lsum, 32);

  if (h > 0) {
    #pragma unroll
    for (int d = 0; d < 4; ++d)
      #pragma unroll
      for (int i = 0; i < 4; ++i) comb[h - 1][lane][d * 4 + i] = oacc[d][i];
    comb[h - 1][lane][16] = lsum;
  }
  __syncthreads();
  if (h == 0) {
    #pragma unroll
    for (int j = 0; j < 3; ++j) {
      #pragma unroll
      for (int d = 0; d < 4; ++d)
        #pragma unroll
        for (int i = 0; i < 4; ++i) oacc[d][i] += comb[j][lane][d * 4 + i];
      lsum += comb[j][lane][16];
    }
    const float rsc = qmask[bh * SEQ + q0 + lr] / fmaxf(lsum, 1e-37f);
    float* orow = out_res + ((size_t)(bh * SEQ + q0 + lr)) * DH;
    #pragma unroll
    for (int d = 0; d < 4; ++d) {
      f32x4 o = { oacc[d][0] * rsc, oacc[d][1] * rsc,
                  oacc[d][2] * rsc, oacc[d][3] * rsc };
      *(f32x4*)(orow + d * 16 + g * 4) = o;
    }
  }
}

// ============================ pass B ============================
// One wave per row: read 4KB f16 strip, l = sum, write 8KB f32 row scaled.
// The reduction orders all loads before stores -> in-place expansion safe.
__global__ __launch_bounds__(256)
void mha_pass_b(const float* __restrict__ qmask,
                float* __restrict__ out_attn)
{
  const int lane = threadIdx.x & 63;
  const int wv   = threadIdx.x >> 6;
  const int row  = blockIdx.x * 4 + wv;

  float* rowp = out_attn + (size_t)row * SEQ;
  const f16x8* src = (const f16x8*)((const f16*)rowp + 2048 + lane * 32);

  f16x8 v0 = src[0], v1 = src[1], v2 = src[2], v3 = src[3];

  float f[32];
  #pragma unroll
  for (int j = 0; j < 8; ++j) {
    f[j]      = (float)v0[j];
    f[8 + j]  = (float)v1[j];
    f[16 + j] = (float)v2[j];
    f[24 + j] = (float)v3[j];
  }
  float lsum = 0.f;
  #pragma unroll
  for (int j = 0; j < 32; ++j) lsum += f[j];
  #pragma unroll
  for (int off = 1; off < 64; off <<= 1) lsum += __shfl_xor(lsum, off);

  const float scale = qmask[row] / fmaxf(lsum, 1e-37f);

  float4* dst = (float4*)(rowp + lane * 32);
  #pragma unroll
  for (int m = 0; m < 8; ++m) {
    float4 o = { f[m * 4 + 0] * scale, f[m * 4 + 1] * scale,
                 f[m * 4 + 2] * scale, f[m * 4 + 3] * scale };
    dst[m] = o;
  }
}

extern "C" void kernel_launch(void* const* d_in, const int* in_sizes, int n_in,
                              void* d_out, int out_size, void* d_ws, size_t ws_size,
                              hipStream_t stream) {
  const float* key   = (const float*)d_in[0];
  const float* value = (const float*)d_in[1];
  const float* query = (const float*)d_in[2];
  const int*   mask  = (const int*)d_in[3];
  const float* qmask = (const float*)d_in[4];

  float* out_res  = (float*)d_out;                       // [16,2048,64]
  float* out_attn = out_res + (size_t)BH * SEQ * DH;     // [16,2048,2048]

  mha_prep<<<dim3(768), dim3(256), 0, stream>>>(key, value, (char*)out_attn);
  mha_packmask<<<dim3(8192), dim3(256), 0, stream>>>(mask, (char*)out_attn);

  mha_pass_a<<<dim3(2048), dim3(256), 0, stream>>>(
      (const char*)out_attn, (const char*)out_attn, (const char*)out_attn,
      query, qmask, out_res, (f16*)out_attn);

  mha_pass_b<<<dim3(BH * SEQ / 4), dim3(256), 0, stream>>>(qmask, out_attn);
}

// Round 10
// 390.423 us; speedup vs baseline: 1.0109x; 1.0109x over previous
//
#include <hip/hip_runtime.h>
#include <hip/hip_bf16.h>

#define BH   16
#define SEQ  2048
#define DH   64

typedef _Float16 f16;
typedef unsigned int u32;
using f32x4 = __attribute__((ext_vector_type(4))) float;
using f16x8 = __attribute__((ext_vector_type(8))) _Float16;
using f16x4 = __attribute__((ext_vector_type(4))) _Float16;

// ---------------- scratch map (first 4 KB "FH" of out_attn rows) ------------
// K   f16 [bh][k][d] : FH rows    0..1023  (chunk (bh*2048+k)>>5, off (k&31)*128+d*2)
// V^T f16 [bh][d][k] : FH rows 1024..2047  (row 1024+bh*64+d, off k*2)
// maskbits [bh][q][w]: FH rows 2048..4095  (256B per q-row: 64 u32 words)
// P' strips (f16) live in SECOND halves (bytes 4096..8191) of every row ->
// byte-disjoint. pass_b overwrites all rows last, so scratch never leaks.

// =================== fused prep: K + V^T + mask bit-pack ===================
__global__ __launch_bounds__(256)
void mha_prep(const float* __restrict__ key, const float* __restrict__ value,
              const int* __restrict__ mask, char* __restrict__ scr)
{
  const int tid = threadIdx.x;
  if (blockIdx.x >= 768) {          // ---- mask pack: 8192 blocks ----
    const int T = (blockIdx.x - 768) * 256 + tid;     // 0 .. 2M-1
    const int* src = mask + (size_t)T * 32;
    u32 bits = 0;
    #pragma unroll
    for (int c = 0; c < 8; ++c) {
      int4 m = *(const int4*)(src + c * 4);
      bits |= (m.x ? 1u : 0u) << (c * 4 + 0);
      bits |= (m.y ? 1u : 0u) << (c * 4 + 1);
      bits |= (m.z ? 1u : 0u) << (c * 4 + 2);
      bits |= (m.w ? 1u : 0u) << (c * 4 + 3);
    }
    const size_t L = (size_t)T * 4;
    *(u32*)(scr + ((size_t)2048 + (L >> 12)) * 8192 + (L & 4095)) = bits;
  } else if (blockIdx.x < 512) {    // ---- K path ----
    const int bh = blockIdx.x >> 5;
    const int k  = (blockIdx.x & 31) * 64 + (tid >> 2);
    const int ds = (tid & 3) * 16;
    const float* src = key + ((size_t)(bh * SEQ + k)) * DH + ds;
    f32x4 a0 = *(const f32x4*)(src);
    f32x4 a1 = *(const f32x4*)(src + 4);
    f32x4 a2 = *(const f32x4*)(src + 8);
    f32x4 a3 = *(const f32x4*)(src + 12);
    f16x8 h0, h1;
    #pragma unroll
    for (int e = 0; e < 4; ++e) {
      h0[e] = (f16)a0[e]; h0[4 + e] = (f16)a1[e];
      h1[e] = (f16)a2[e]; h1[4 + e] = (f16)a3[e];
    }
    char* dst = scr + ((size_t)((bh * SEQ + k) >> 5)) * 8192 + (k & 31) * 128 + ds * 2;
    *(f16x8*)dst        = h0;
    *(f16x8*)(dst + 16) = h1;
  } else {                          // ---- V^T path ----
    __shared__ f16 Vl[64][136];
    const int vb = blockIdx.x - 512;
    const int bh = vb >> 4;
    const int kc = (vb & 15) * 128;
    {
      const int kl = tid >> 1, dh = (tid & 1) * 32;
      const float* src = value + ((size_t)(bh * SEQ + kc + kl)) * DH + dh;
      f32x4 a[8];
      #pragma unroll
      for (int j = 0; j < 8; ++j) a[j] = *(const f32x4*)(src + j * 4);
      #pragma unroll
      for (int j = 0; j < 32; ++j) Vl[dh + j][kl] = (f16)a[j >> 2][j & 3];
    }
    __syncthreads();
    {
      const int d = tid >> 2, ks = (tid & 3) * 32;
      char* dst = scr + ((size_t)(1024 + bh * 64 + d)) * 8192 + (kc + ks) * 2;
      #pragma unroll
      for (int m = 0; m < 4; ++m)
        *(f16x8*)(dst + m * 16) = *(const f16x8*)&Vl[d][ks + m * 8];
    }
  }
}

// ============================ pass A ============================
struct Pipe {
  f16x8 ka0, ka1, kb0, kb1;                 // K-frags, substeps a/b
  f16x4 va0, va1, va2, va3, vb0, vb1, vb2, vb3;  // V^T frags, 4 d-blocks
  u32   mw;                                 // 32 mask bits
};

static __device__ __forceinline__ void pref(Pipe& P, const char* kscr,
                                            const char* vrow, const char* pmrow,
                                            int bh, int K, int lr, int g) {
  const char* kab = kscr + ((size_t)(((bh << 11) + K) >> 5)) * 8192;
  P.ka0 = *(const f16x8*)(kab + lr * 128 + g * 16);
  P.ka1 = *(const f16x8*)(kab + lr * 128 + 64 + g * 16);
  P.kb0 = *(const f16x8*)(kab + (16 + lr) * 128 + g * 16);
  P.kb1 = *(const f16x8*)(kab + (16 + lr) * 128 + 64 + g * 16);
  P.va0 = *(const f16x4*)(vrow +  0 * 8192 + (K + g * 4) * 2);
  P.va1 = *(const f16x4*)(vrow + 16 * 8192 + (K + g * 4) * 2);
  P.va2 = *(const f16x4*)(vrow + 32 * 8192 + (K + g * 4) * 2);
  P.va3 = *(const f16x4*)(vrow + 48 * 8192 + (K + g * 4) * 2);
  P.vb0 = *(const f16x4*)(vrow +  0 * 8192 + (K + 16 + g * 4) * 2);
  P.vb1 = *(const f16x4*)(vrow + 16 * 8192 + (K + 16 + g * 4) * 2);
  P.vb2 = *(const f16x4*)(vrow + 32 * 8192 + (K + 16 + g * 4) * 2);
  P.vb3 = *(const f16x4*)(vrow + 48 * 8192 + (K + 16 + g * 4) * 2);
  P.mw  = *(const u32*)(pmrow + (K >> 5) * 4);
}

static __device__ __forceinline__ void step(const Pipe& P, int K,
                                            const f16x8& qf0, const f16x8& qf1,
                                            f32x4 (&oacc)[4], float& lsum,
                                            f16* srow, int g) {
  f32x4 sa = {0.f, 0.f, 0.f, 0.f}, sb = {0.f, 0.f, 0.f, 0.f};
  sa = __builtin_amdgcn_mfma_f32_16x16x32_f16(P.ka0, qf0, sa, 0, 0, 0);
  sa = __builtin_amdgcn_mfma_f32_16x16x32_f16(P.ka1, qf1, sa, 0, 0, 0);
  sb = __builtin_amdgcn_mfma_f32_16x16x32_f16(P.kb0, qf0, sb, 0, 0, 0);
  sb = __builtin_amdgcn_mfma_f32_16x16x32_f16(P.kb1, qf1, sb, 0, 0, 0);

  const int sha = g * 4, shb = 16 + g * 4;
  const float a0 = ((P.mw >> (sha + 0)) & 1u) ? 0.f : __expf(sa[0] * 0.125f);
  const float a1 = ((P.mw >> (sha + 1)) & 1u) ? 0.f : __expf(sa[1] * 0.125f);
  const float a2 = ((P.mw >> (sha + 2)) & 1u) ? 0.f : __expf(sa[2] * 0.125f);
  const float a3 = ((P.mw >> (sha + 3)) & 1u) ? 0.f : __expf(sa[3] * 0.125f);
  const float b0 = ((P.mw >> (shb + 0)) & 1u) ? 0.f : __expf(sb[0] * 0.125f);
  const float b1 = ((P.mw >> (shb + 1)) & 1u) ? 0.f : __expf(sb[1] * 0.125f);
  const float b2 = ((P.mw >> (shb + 2)) & 1u) ? 0.f : __expf(sb[2] * 0.125f);
  const float b3 = ((P.mw >> (shb + 3)) & 1u) ? 0.f : __expf(sb[3] * 0.125f);
  lsum += ((a0 + a1) + (a2 + a3)) + ((b0 + b1) + (b2 + b3));
  f16x4 pa = { (f16)a0, (f16)a1, (f16)a2, (f16)a3 };
  f16x4 pb = { (f16)b0, (f16)b1, (f16)b2, (f16)b3 };

  *(f16x4*)&srow[K + g * 4]      = pa;
  *(f16x4*)&srow[K + 16 + g * 4] = pb;

  oacc[0] = __builtin_amdgcn_mfma_f32_16x16x16f16(P.va0, pa, oacc[0], 0, 0, 0);
  oacc[1] = __builtin_amdgcn_mfma_f32_16x16x16f16(P.va1, pa, oacc[1], 0, 0, 0);
  oacc[2] = __builtin_amdgcn_mfma_f32_16x16x16f16(P.va2, pa, oacc[2], 0, 0, 0);
  oacc[3] = __builtin_amdgcn_mfma_f32_16x16x16f16(P.va3, pa, oacc[3], 0, 0, 0);
  oacc[0] = __builtin_amdgcn_mfma_f32_16x16x16f16(P.vb0, pb, oacc[0], 0, 0, 0);
  oacc[1] = __builtin_amdgcn_mfma_f32_16x16x16f16(P.vb1, pb, oacc[1], 0, 0, 0);
  oacc[2] = __builtin_amdgcn_mfma_f32_16x16x16f16(P.vb2, pb, oacc[2], 0, 0, 0);
  oacc[3] = __builtin_amdgcn_mfma_f32_16x16x16f16(P.vb3, pb, oacc[3], 0, 0, 0);
}

// Wave-autonomous, all loop loads L2-resident, no in-loop LDS/barriers.
// 2-deep named-register pipeline (E/O), loads pinned early by sched_barrier.
__global__ __launch_bounds__(256, 4)
void mha_pass_a(const char* __restrict__ kscr, const char* __restrict__ vscr,
                const char* __restrict__ pmscr,
                const float* __restrict__ query,
                const float* __restrict__ qmask,
                float* __restrict__ out_res, f16* __restrict__ strip)
{
  __shared__ float comb[3][64][17];
  const int tid  = threadIdx.x;
  const int lane = tid & 63;
  const int h    = tid >> 6;          // wave = k-quarter 0..3
  const int lr   = lane & 15;
  const int g    = lane >> 4;

  // XCD swizzle: 2048 blocks -> 256/XCD -> 2 bh per XCD (scratch L2-resident)
  const int idx = ((blockIdx.x & 7) << 8) + (blockIdx.x >> 3);
  const int bh  = idx >> 7;
  const int q0  = (idx & 127) << 4;

  // ---- Q fragments (f32 -> f16 registers) ----
  f16x8 qf0, qf1;
  {
    const float* qrow = query + ((size_t)(bh * SEQ + q0 + lr)) * DH;
    f32x4 a0 = *(const f32x4*)(qrow + g * 8);
    f32x4 a1 = *(const f32x4*)(qrow + g * 8 + 4);
    f32x4 a2 = *(const f32x4*)(qrow + 32 + g * 8);
    f32x4 a3 = *(const f32x4*)(qrow + 32 + g * 8 + 4);
    #pragma unroll
    for (int e = 0; e < 4; ++e) {
      qf0[e] = (f16)a0[e]; qf0[4 + e] = (f16)a1[e];
      qf1[e] = (f16)a2[e]; qf1[4 + e] = (f16)a3[e];
    }
  }

  f16* srow = strip + ((size_t)(bh * SEQ + q0 + lr)) * 4096 + 2048;
  const char* vrow = vscr + ((size_t)(1024 + bh * 64 + lr)) * 8192;
  const size_t L = ((size_t)((bh << 11) + q0 + lr)) << 8;
  const char* pmrow = pmscr + ((size_t)2048 + (L >> 12)) * 8192 + (L & 4095);

  f32x4 oacc[4];
  #pragma unroll
  for (int d = 0; d < 4; ++d) oacc[d] = (f32x4){0.f, 0.f, 0.f, 0.f};
  float lsum = 0.f;

  const int base = h * 512;
  Pipe E, O;
  pref(E, kscr, vrow, pmrow, bh, base, lr, g);

  for (int it = 0; it < 8; ++it) {
    const int K0 = base + it * 64;
    pref(O, kscr, vrow, pmrow, bh, K0 + 32, lr, g);
    __builtin_amdgcn_sched_barrier(0);     // pin O-loads before E-compute
    step(E, K0, qf0, qf1, oacc, lsum, srow, g);
    if (it < 7) pref(E, kscr, vrow, pmrow, bh, K0 + 64, lr, g);
    __builtin_amdgcn_sched_barrier(0);     // pin E-loads before O-compute
    step(O, K0 + 32, qf0, qf1, oacc, lsum, srow, g);
  }

  // ---- row partials -> combine 4 quarters (only barrier in the kernel) ----
  lsum += __shfl_xor(lsum, 16);
  lsum += __shfl_xor(lsum, 32);

  if (h > 0) {
    #pragma unroll
    for (int d = 0; d < 4; ++d)
      #pragma unroll
      for (int i = 0; i < 4; ++i) comb[h - 1][lane][d * 4 + i] = oacc[d][i];
    comb[h - 1][lane][16] = lsum;
  }
  __syncthreads();
  if (h == 0) {
    #pragma unroll
    for (int j = 0; j < 3; ++j) {
      #pragma unroll
      for (int d = 0; d < 4; ++d)
        #pragma unroll
        for (int i = 0; i < 4; ++i) oacc[d][i] += comb[j][lane][d * 4 + i];
      lsum += comb[j][lane][16];
    }
    const float rsc = qmask[bh * SEQ + q0 + lr] / fmaxf(lsum, 1e-37f);
    float* orow = out_res + ((size_t)(bh * SEQ + q0 + lr)) * DH;
    #pragma unroll
    for (int d = 0; d < 4; ++d) {
      f32x4 o = { oacc[d][0] * rsc, oacc[d][1] * rsc,
                  oacc[d][2] * rsc, oacc[d][3] * rsc };
      *(f32x4*)(orow + d * 16 + g * 4) = o;
    }
  }
}

// ============================ pass B ============================
// One wave per row: read 4KB f16 strip, l = sum, write 8KB f32 row scaled.
// The reduction orders all loads before stores -> in-place expansion safe.
__global__ __launch_bounds__(256)
void mha_pass_b(const float* __restrict__ qmask,
                float* __restrict__ out_attn)
{
  const int lane = threadIdx.x & 63;
  const int wv   = threadIdx.x >> 6;
  const int row  = blockIdx.x * 4 + wv;

  float* rowp = out_attn + (size_t)row * SEQ;
  const f16x8* src = (const f16x8*)((const f16*)rowp + 2048 + lane * 32);

  f16x8 v0 = src[0], v1 = src[1], v2 = src[2], v3 = src[3];

  float f[32];
  #pragma unroll
  for (int j = 0; j < 8; ++j) {
    f[j]      = (float)v0[j];
    f[8 + j]  = (float)v1[j];
    f[16 + j] = (float)v2[j];
    f[24 + j] = (float)v3[j];
  }
  float lsum = 0.f;
  #pragma unroll
  for (int j = 0; j < 32; ++j) lsum += f[j];
  #pragma unroll
  for (int off = 1; off < 64; off <<= 1) lsum += __shfl_xor(lsum, off);

  const float scale = qmask[row] / fmaxf(lsum, 1e-37f);

  float4* dst = (float4*)(rowp + lane * 32);
  #pragma unroll
  for (int m = 0; m < 8; ++m) {
    float4 o = { f[m * 4 + 0] * scale, f[m * 4 + 1] * scale,
                 f[m * 4 + 2] * scale, f[m * 4 + 3] * scale };
    dst[m] = o;
  }
}

extern "C" void kernel_launch(void* const* d_in, const int* in_sizes, int n_in,
                              void* d_out, int out_size, void* d_ws, size_t ws_size,
                              hipStream_t stream) {
  const float* key   = (const float*)d_in[0];
  const float* value = (const float*)d_in[1];
  const float* query = (const float*)d_in[2];
  const int*   mask  = (const int*)d_in[3];
  const float* qmask = (const float*)d_in[4];

  float* out_res  = (float*)d_out;                       // [16,2048,64]
  float* out_attn = out_res + (size_t)BH * SEQ * DH;     // [16,2048,2048]

  mha_prep<<<dim3(768 + 8192), dim3(256), 0, stream>>>(
      key, value, mask, (char*)out_attn);

  mha_pass_a<<<dim3(2048), dim3(256), 0, stream>>>(
      (const char*)out_attn, (const char*)out_attn, (const char*)out_attn,
      query, qmask, out_res, (f16*)out_attn);

  mha_pass_b<<<dim3(BH * SEQ / 4), dim3(256), 0, stream>>>(qmask, out_attn);
}